// Round 11
// baseline (179.849 us; speedup 1.0000x reference)
//
#include <hip/hip_runtime.h>
#include <math.h>

// Problem constants (from reference): T=128, B=2048, D=256, ALPHA=0.5, VTH=1.0
#define TT 128
#define BB 2048
#define DDIM 256
#define BD (BB * DDIM)
#define TPB 64  // one wave per block; 32 KiB LDS -> 5 blocks/CU

// GL coefficients c[j] = prod_{i=1..j} (1 - (1+alpha)/i), computed in f64 then
// cast to f32 — exactly mirrors _gl_coeffs (float64 cumprod -> float32 cast).
struct Coeffs {
    float c[TT + 1];
};
static constexpr Coeffs make_coeffs() {
    Coeffs r{};
    r.c[0] = 1.0f;
    double cur = 1.0;
    for (int j = 1; j <= TT; ++j) {
        cur *= (1.0 - 1.5 / (double)j);  // (1+alpha) = 1.5
        r.c[j] = (float)cur;
    }
    return r;
}
static constexpr Coeffs CO = make_coeffs();

// One thread per (b,d) sequence — 16x16-tiled triangular convolution, y-history
// in LDS (slot-major), SOFTWARE-PIPELINED at the step-block level.
//
// R10 result: LDS home is clean (no scratch, 12.2K instrs/wave = 1.2/FMA) but
// occupancy is LDS-capped at ~1.25 waves/SIMD and VALUBusy=41%: the diagonal
// tile is a ~700-cycle dependent chain a single in-order wave can't hide.
// Issue floor at this instr count is ~81 us; the lever is bubble-filling:
//   iter K: (1) accB  = block K+1's tiles I=0..K-1   [LDS, independent]
//           (2) diagonal of block K from accA -> yn  [serial chain]
//           (3) accB += tile I=K straight from yn REGISTERS (no LDS read);
//               256 independent FMAs that become ready per-yn[r], which the
//               compiler scheduler interleaves into the diagonal's stalls.
// Bit-exactness: block K+1 accumulates tiles I ascending (0..K-1, then K),
// s ascending inside each tile — the exact chain of R1/R7/R10 (all passed).
// Spike stores are nontemporal: 268 MB write stream stops evicting x from L3.
__global__ __launch_bounds__(TPB) void gl_if_kernel(const float* __restrict__ x,
                                                    float* __restrict__ sp) {
    __shared__ float ylds[TT * TPB];  // 32 KiB, slot-major: ylds[s*TPB + tid]
    const int tid = threadIdx.x;
    const int g = blockIdx.x * TPB + tid;  // (b,d) flat index

    float accA[16], accB[16], xv[16], xnv[16];

#pragma unroll
    for (int r = 0; r < 16; ++r) xv[r] = x[g + (size_t)r * BD];
#pragma unroll
    for (int r = 0; r < 16; ++r) accA[r] = 0.0f;

#pragma unroll
    for (int K = 0; K < TT / 16; ++K) {
        // prefetch next block's x during this block's FMA work
        if (K < TT / 16 - 1) {
#pragma unroll
            for (int r = 0; r < 16; ++r) {
                xnv[r] = x[g + (size_t)(16 * (K + 1) + r) * BD];
            }
        }

        // (1) pre-diagonal: block K+1's full tiles I = 0..K-1 from LDS.
        //     step r of block K+1: k = 16(K+1)+r+1, slot 16I+s ->
        //     coeff j = 16(K+1-I) + r - s.
        if (K < TT / 16 - 1) {
#pragma unroll
            for (int r = 0; r < 16; ++r) accB[r] = 0.0f;
#pragma unroll
            for (int I = 0; I < K; ++I) {
                float yt[16];
#pragma unroll
                for (int s = 0; s < 16; ++s) {
                    yt[s] = ylds[(16 * I + s) * TPB + tid];
                }
#pragma unroll
                for (int r = 0; r < 16; ++r) {
#pragma unroll
                    for (int s = 0; s < 16; ++s) {
                        accB[r] = fmaf(CO.c[16 * (K + 1 - I) + r - s], yt[s],
                                       accB[r]);
                    }
                }
            }
        }

        // (2) diagonal tile + spike/reset for block K (the serial part)
        float yn[16];
#pragma unroll
        for (int r = 0; r < 16; ++r) {
            float a = accA[r];
#pragma unroll
            for (int s = 0; s < r; ++s) {
                a = fmaf(CO.c[r - s], yn[s], a);
            }
            const float men0 = xv[r] - a;
            const float spike = (men0 > 1.0f) ? 1.0f : 0.0f;
            yn[r] = men0 - spike;  // VTH = 1.0
            __builtin_nontemporal_store(spike,
                                        &sp[g + (size_t)(16 * K + r) * BD]);
        }

        // commit tile K to the LDS history; clobber stops store->load
        // forwarding from resurrecting the register-home problem (R9 lesson)
#pragma unroll
        for (int r = 0; r < 16; ++r) ylds[(16 * K + r) * TPB + tid] = yn[r];
        asm volatile("" ::: "memory");

        // (3) post-diagonal: block K+1's tile I=K straight from yn registers.
        //     coeff j = 16 + r - s (c[1..31]). Independent FMAs that fill the
        //     diagonal chain's issue bubbles.
        if (K < TT / 16 - 1) {
#pragma unroll
            for (int r = 0; r < 16; ++r) {
#pragma unroll
                for (int s = 0; s < 16; ++s) {
                    accB[r] = fmaf(CO.c[16 + r - s], yn[s], accB[r]);
                }
            }
#pragma unroll
            for (int r = 0; r < 16; ++r) accA[r] = accB[r];
#pragma unroll
            for (int r = 0; r < 16; ++r) xv[r] = xnv[r];
        }
    }
}

// Lorentz expmap: per row b, vv = -v0^2 + sum_{d>=1} vd^2; s = sqrt(max(vv,eps));
// out = cosh(s)*z + (sinh(s)/s)*v.  One block per row, one thread per d.
__global__ __launch_bounds__(256) void expmap_kernel(const float* __restrict__ v,
                                                     const float* __restrict__ z,
                                                     float* __restrict__ out) {
    const int b = blockIdx.x;
    const int d = threadIdx.x;
    const size_t idx = (size_t)b * DDIM + d;
    const float vd = v[idx];

    float term = vd * vd;
    if (d == 0) term = -term;

    // reduce across the 256-thread block (4 waves of 64)
    float sum = term;
#pragma unroll
    for (int off = 32; off > 0; off >>= 1) sum += __shfl_down(sum, off, 64);

    __shared__ float ws[4];
    if ((threadIdx.x & 63) == 0) ws[threadIdx.x >> 6] = sum;
    __syncthreads();
    const float vv = ws[0] + ws[1] + ws[2] + ws[3];

    const float s2 = fmaxf(vv, 1e-6f);
    const float s = sqrtf(s2);
    const float ch = coshf(s);
    const float shs = sinhf(s) / s;

    out[idx] = ch * z[idx] + shs * vd;
}

extern "C" void kernel_launch(void* const* d_in, const int* in_sizes, int n_in,
                              void* d_out, int out_size, void* d_ws, size_t ws_size,
                              hipStream_t stream) {
    const float* x_seq = (const float*)d_in[0];
    const float* v_seq = (const float*)d_in[1];
    const float* z_seq = (const float*)d_in[2];

    float* s_out = (float*)d_out;                       // [T,B,D] spikes
    float* z_out = (float*)d_out + (size_t)TT * BD;     // [B,D] expmap

    gl_if_kernel<<<BD / TPB, TPB, 0, stream>>>(x_seq, s_out);
    expmap_kernel<<<BB, DDIM, 0, stream>>>(v_seq, z_seq, z_out);
}